// Round 7
// baseline (693.979 us; speedup 1.0000x reference)
//
#include <hip/hip_runtime.h>
#include <math.h>

#define NEG_SLOPE 0.2f
#define NBUCK 512      // dst buckets of 256 nodes
#define BHCHUNK 8192   // edges per histogram block
#define BCHUNK 4096    // edges per k_bin block
#define DCHUNK 2048    // nodes per degree-sort block

typedef __attribute__((ext_vector_type(8))) short short8;   // 8 bf16 (MFMA A/B frag)
typedef __attribute__((ext_vector_type(4))) float f32x4;    // MFMA C/D frag

__device__ __forceinline__ unsigned short bf16rne(float x) {
    unsigned u = __float_as_uint(x);
    u += 0x7fffu + ((u >> 16) & 1u);
    return (unsigned short)(u >> 16);
}
__device__ __forceinline__ unsigned pack_bf2(float x, float y) {
    unsigned ux = __float_as_uint(x), uy = __float_as_uint(y);
    ux = (ux + 0x7fffu + ((ux >> 16) & 1u)) >> 16;
    uy = (uy + 0x7fffu + ((uy >> 16) & 1u)) & 0xffff0000u;
    return ux | uy;
}

// ---------------- fused front: bucket-hist + x->bf16 + W->Wt ----------------
__global__ __launch_bounds__(256) void k_front(
    const int* __restrict__ dst, int* __restrict__ bcnt, int E,
    const float4* __restrict__ x, uint4* __restrict__ Xb, int n8,
    const float* __restrict__ w0, const float* __restrict__ w1,
    const float* __restrict__ w2, unsigned short* __restrict__ Wt,
    int nbB, int nbCvt) {
    __shared__ int cnt[NBUCK];
    int bb = blockIdx.x, t = threadIdx.x;
    if (bb < nbB) {
        for (int i = t; i < NBUCK; i += 256) cnt[i] = 0;
        __syncthreads();
        int e0 = bb * BHCHUNK;
        int n = min(BHCHUNK, E - e0);
        for (int i = t; i < n; i += 256) atomicAdd(&cnt[dst[e0 + i] >> 8], 1);
        __syncthreads();
        for (int i = t; i < NBUCK; i += 256)
            if (cnt[i]) atomicAdd(&bcnt[i], cnt[i]);
    } else if (bb < nbB + nbCvt) {
        int id = (bb - nbB) * 256 + t;
        if (id < n8) {
            float4 a = x[id * 2], b = x[id * 2 + 1];
            uint4 o;
            o.x = pack_bf2(a.x, a.y);
            o.y = pack_bf2(a.z, a.w);
            o.z = pack_bf2(b.x, b.y);
            o.w = pack_bf2(b.z, b.w);
            Xb[id] = o;
        }
    } else {
        int id = (bb - nbB - nbCvt) * 256 + t;    // 3*16384 ids
        int layer = id >> 14, rem = id & 16383;
        int k = rem >> 7, n = rem & 127;
        const float* W = (layer == 0) ? w0 : (layer == 1) ? w1 : w2;
        Wt[layer * 16384 + n * 128 + k] = bf16rne(W[k * 128 + n]);
    }
}

// ---------------- bucket scan (one block, 512 threads) ----------------
__global__ void k_bscan(const int* __restrict__ bcnt, int* __restrict__ bbase,
                        int* __restrict__ bcur, int* __restrict__ rowstart,
                        int N, int E) {
    __shared__ int sd[NBUCK];
    int t = threadIdx.x;
    int c = bcnt[t];
    sd[t] = c;
    __syncthreads();
    for (int s = 1; s < NBUCK; s <<= 1) {
        int x = (t >= s) ? sd[t - s] : 0;
        __syncthreads();
        sd[t] += x;
        __syncthreads();
    }
    int excl = sd[t] - c;
    bbase[t] = excl;
    bcur[t] = excl;
    if (t == NBUCK - 1) bbase[NBUCK] = excl + c;   // == E
    if (t == 0) rowstart[N] = E;
}

// ---------------- bin edges into buckets (contiguous packed runs) ----------------
__global__ __launch_bounds__(256) void k_bin(
    const int* __restrict__ src, const int* __restrict__ dst,
    int* __restrict__ bcur, unsigned* __restrict__ packed, int E) {
    __shared__ int cnt[NBUCK];
    __shared__ int gbase[NBUCK];
    for (int i = threadIdx.x; i < NBUCK; i += 256) cnt[i] = 0;
    __syncthreads();
    int e0 = blockIdx.x * BCHUNK;
    int n = min(BCHUNK, E - e0);
    for (int i = threadIdx.x; i < n; i += 256)
        atomicAdd(&cnt[dst[e0 + i] >> 8], 1);
    __syncthreads();
    for (int i = threadIdx.x; i < NBUCK; i += 256) {
        int c = cnt[i];
        gbase[i] = c ? atomicAdd(&bcur[i], c) : 0;
        cnt[i] = 0;
    }
    __syncthreads();
    for (int i = threadIdx.x; i < n; i += 256) {
        int d = dst[e0 + i];
        int b = d >> 8;
        int o = atomicAdd(&cnt[b], 1);
        packed[gbase[b] + o] = ((unsigned)src[e0 + i] << 8) | (unsigned)(d & 255);
    }
}

// ---------------- per-bucket: node hist + scan -> rowstart; place via LDS cursors ----
// cpack entry = (dst_local<<17) | src  (src < 2^17).
__global__ __launch_bounds__(256) void k_place2(
    const unsigned* __restrict__ packed, const int* __restrict__ bbase,
    int* __restrict__ rowstart, unsigned* __restrict__ cpack, int N) {
    __shared__ int cnt[256], sd[256], lcur[256];
    int b = blockIdx.x, t = threadIdx.x;
    int base = bbase[b], end = bbase[b + 1];
    cnt[t] = 0;
    __syncthreads();
    for (int i = base + t; i < end; i += 256)
        atomicAdd(&cnt[packed[i] & 255u], 1);
    __syncthreads();
    sd[t] = cnt[t];
    __syncthreads();
    for (int s = 1; s < 256; s <<= 1) {
        int x = (t >= s) ? sd[t - s] : 0;
        __syncthreads();
        sd[t] += x;
        __syncthreads();
    }
    int excl = sd[t] - cnt[t];
    int gid = (b << 8) + t;
    if (gid < N) rowstart[gid] = base + excl;
    lcur[t] = base + excl;
    __syncthreads();
    for (int i = base + t; i < end; i += 256) {
        unsigned p = packed[i];
        unsigned dl = p & 255u;
        int pos = atomicAdd(&lcur[dl], 1);
        cpack[pos] = (dl << 17) | (p >> 8);
    }
}

// ---------------- degree sort: order[] groups equal-degree nodes ----------------
__global__ __launch_bounds__(256) void k_dsort1(
    const int* __restrict__ rowstart, int* __restrict__ dcnt, int N) {
    __shared__ int cnt[64];
    int t = threadIdx.x;
    if (t < 64) cnt[t] = 0;
    __syncthreads();
    int n0 = blockIdx.x * DCHUNK;
    int n = min(DCHUNK, N - n0);
    for (int i = t; i < n; i += 256) {
        int d = rowstart[n0 + i + 1] - rowstart[n0 + i];
        atomicAdd(&cnt[min(d, 63)], 1);
    }
    __syncthreads();
    if (t < 64 && cnt[t]) atomicAdd(&dcnt[t], cnt[t]);
}

__global__ void k_dscan(const int* __restrict__ dcnt, int* __restrict__ dcur) {
    __shared__ int sd[64];
    int t = threadIdx.x;   // 64 threads
    int c = dcnt[t];
    sd[t] = c;
    __syncthreads();
    for (int s = 1; s < 64; s <<= 1) {
        int x = (t >= s) ? sd[t - s] : 0;
        __syncthreads();
        sd[t] += x;
        __syncthreads();
    }
    dcur[t] = sd[t] - c;
}

__global__ __launch_bounds__(256) void k_dsort2(
    const int* __restrict__ rowstart, int* __restrict__ dcur,
    int* __restrict__ order, int N) {
    __shared__ int cnt[64], gbase[64];
    int t = threadIdx.x;
    if (t < 64) cnt[t] = 0;
    __syncthreads();
    int n0 = blockIdx.x * DCHUNK;
    int n = min(DCHUNK, N - n0);
    for (int i = t; i < n; i += 256)
        atomicAdd(&cnt[min(rowstart[n0 + i + 1] - rowstart[n0 + i], 63)], 1);
    __syncthreads();
    if (t < 64) {
        int c = cnt[t];
        gbase[t] = c ? atomicAdd(&dcur[t], c) : 0;
        cnt[t] = 0;
    }
    __syncthreads();
    for (int i = t; i < n; i += 256) {
        int b = min(rowstart[n0 + i + 1] - rowstart[n0 + i], 63);
        int o = atomicAdd(&cnt[b], 1);
        order[gbase[b] + o] = n0 + i;
    }
}

// ---------------- MFMA GEMM + el/er epilogue (unchanged) ----------------
__global__ __launch_bounds__(256) void k_gemm(
    const unsigned short* __restrict__ Ab,   // [M][128] bf16
    const unsigned short* __restrict__ Wt,   // [128 n][128 k] bf16
    const float* __restrict__ alv, const float* __restrict__ arv,
    unsigned short* __restrict__ Fb,         // [M][128] bf16
    float* __restrict__ el, float* __restrict__ er, int M) {
    __shared__ unsigned short cst[4][32][128];
    int t = threadIdx.x;
    int wv = t >> 6, l = t & 63;
    int l15 = l & 15, quad = l >> 4;
    int row0 = blockIdx.x * 128 + wv * 32;

    f32x4 acc[2][8];
#pragma unroll
    for (int mi = 0; mi < 2; mi++)
#pragma unroll
        for (int nt = 0; nt < 8; nt++)
            acc[mi][nt] = (f32x4){0.f, 0.f, 0.f, 0.f};

    int rA0 = min(row0 + l15, M - 1);
    int rA1 = min(row0 + 16 + l15, M - 1);
    const uint4* pA0 = (const uint4*)(Ab + (size_t)rA0 * 128) + quad;
    const uint4* pA1 = (const uint4*)(Ab + (size_t)rA1 * 128) + quad;
    const uint4* pW = (const uint4*)Wt;

#pragma unroll
    for (int ks = 0; ks < 4; ks++) {
        union { uint4 u; short8 s; } a0, a1, b[8];
        a0.u = pA0[ks * 4];
        a1.u = pA1[ks * 4];
#pragma unroll
        for (int nt = 0; nt < 8; nt++)
            b[nt].u = pW[(nt * 16 + l15) * 16 + quad + ks * 4];
#pragma unroll
        for (int nt = 0; nt < 8; nt++) {
            acc[0][nt] = __builtin_amdgcn_mfma_f32_16x16x32_bf16(a0.s, b[nt].s, acc[0][nt], 0, 0, 0);
            acc[1][nt] = __builtin_amdgcn_mfma_f32_16x16x32_bf16(a1.s, b[nt].s, acc[1][nt], 0, 0, 0);
        }
    }

#pragma unroll
    for (int mi = 0; mi < 2; mi++)
#pragma unroll
        for (int nt = 0; nt < 8; nt++)
#pragma unroll
            for (int r = 0; r < 4; r++)
                cst[wv][mi * 16 + quad * 4 + r][nt * 16 + l15] = bf16rne(acc[mi][nt][r]);

    int rrow = l >> 1;
    int cb = (l & 1) * 64;
    int grow = row0 + rrow;
    bool ok = grow < M;
    float pe[2] = {0.f, 0.f}, pr[2] = {0.f, 0.f};
#pragma unroll
    for (int i = 0; i < 8; i++) {
        uint4 v = *(const uint4*)&cst[wv][rrow][cb + i * 8];
        if (ok) ((uint4*)(Fb + (size_t)grow * 128 + cb))[i] = v;
        int hi = i >> 2;
        int c0 = cb + i * 8;
        unsigned uu[4] = {v.x, v.y, v.z, v.w};
#pragma unroll
        for (int q = 0; q < 4; q++) {
            float fa = __uint_as_float(uu[q] << 16);
            float fb = __uint_as_float(uu[q] & 0xffff0000u);
            pe[hi] += fa * alv[c0 + 2 * q] + fb * alv[c0 + 2 * q + 1];
            pr[hi] += fa * arv[c0 + 2 * q] + fb * arv[c0 + 2 * q + 1];
        }
    }
    float qe0 = __shfl_xor(pe[0], 1, 64), qe1 = __shfl_xor(pe[1], 1, 64);
    float qr0 = __shfl_xor(pr[0], 1, 64), qr1 = __shfl_xor(pr[1], 1, 64);
    if (((l & 1) == 0) && ok) {
        *(float4*)&el[(size_t)grow * 4] = make_float4(pe[0], pe[1], qe0, qe1);
        *(float4*)&er[(size_t)grow * 4] = make_float4(pr[0], pr[1], qr0, qr1);
    }
}

// ---------------- edge attention -> normalized alpha ----------------
// Two-pass per bucket: pass1 p=exp(leaky(el[s]+er[d])) -> pw, LDS s+=p;
// invert; pass2 pw *= 1/s. k_aggr then needs no denominator at all.
__global__ __launch_bounds__(256) void k_edge(
    const unsigned* __restrict__ cpack, const int* __restrict__ bbase,
    const float4* __restrict__ el4, const float4* __restrict__ er4,
    float4* __restrict__ pw4) {
    __shared__ float sld[256 * 4];
    int b = blockIdx.x, t = threadIdx.x;
    int base = bbase[b], end = bbase[b + 1];
#pragma unroll
    for (int k = 0; k < 4; k++) sld[t * 4 + k] = 0.f;
    __syncthreads();
    for (int i = base + t; i < end; i += 256) {
        unsigned w = cpack[i];
        int s = (int)(w & 0x1ffffu);
        int dl = (int)(w >> 17);
        float4 l = el4[s], r = er4[(b << 8) + dl];
        float4 o;
        float e;
        e = l.x + r.x; e = fmaxf(e, NEG_SLOPE * e); o.x = __expf(e);
        e = l.y + r.y; e = fmaxf(e, NEG_SLOPE * e); o.y = __expf(e);
        e = l.z + r.z; e = fmaxf(e, NEG_SLOPE * e); o.z = __expf(e);
        e = l.w + r.w; e = fmaxf(e, NEG_SLOPE * e); o.w = __expf(e);
        pw4[i] = o;
        atomicAdd(&sld[dl * 4 + 0], o.x);
        atomicAdd(&sld[dl * 4 + 1], o.y);
        atomicAdd(&sld[dl * 4 + 2], o.z);
        atomicAdd(&sld[dl * 4 + 3], o.w);
    }
    __syncthreads();
#pragma unroll
    for (int k = 0; k < 4; k++) sld[t * 4 + k] = 1.f / (sld[t * 4 + k] + 1e-9f);
    __syncthreads();
    for (int i = base + t; i < end; i += 256) {
        unsigned w = cpack[i];
        int dl = (int)(w >> 17);
        float4 p = pw4[i];
        float4 iv = *(float4*)&sld[dl * 4];
        p.x *= iv.x; p.y *= iv.y; p.z *= iv.z; p.w *= iv.w;
        pw4[i] = p;
    }
}

// ---------------- aggregation: 4 nodes/wave, 16 lanes x 8 features ----------
// Nodes taken via degree-sorted order[] -> the 4 nodes in a wave have ~equal
// degree (nccmax ~= ncc, minimal masked work). Lane l16 owns features
// [l16*8, l16*8+8) = one uint4 of packed bf16 per gathered row; alpha
// pre-normalized (no denominator). Ping-pong 8-edge chunks.
template <int OUT_BF16>
__global__ __launch_bounds__(256) void k_aggr(
    const int* __restrict__ rowstart, const int* __restrict__ order,
    const unsigned* __restrict__ cpack, const float* __restrict__ alphap,
    const uint4* __restrict__ F4, void* __restrict__ outp, int N, int E) {
    int lane = threadIdx.x & 63;
    int sub = lane >> 4;           // node slot in wave
    int l16 = lane & 15;
    int widx = blockIdx.x * 16 + ((threadIdx.x >> 6) << 2) + sub;
    bool active = widx < N;
    int node = order[active ? widx : N - 1];
    int start = rowstart[node];
    int dg = active ? (rowstart[node + 1] - start) : 0;
    int h = l16 >> 2;

    float a0 = 0.f, a1 = 0.f, a2 = 0.f, a3 = 0.f;
    float a4 = 0.f, a5 = 0.f, a6 = 0.f, a7 = 0.f;

    int ncc = (dg + 7) >> 3;
    int m = max(ncc, __shfl_xor(ncc, 16, 64));
    int nccmax = max(m, __shfl_xor(m, 32, 64));
    int full = dg >> 3;
    int mf = min(full, __shfl_xor(full, 16, 64));
    int minfull = min(mf, __shfl_xor(mf, 32, 64));   // wave-uniform

    auto loadc = [&](int c, uint4* fb, float* pb) {
        int j = c << 3;
        if (c < minfull) {
#pragma unroll
            for (int u = 0; u < 8; u++) {
                int e = start + j + u;
                int s = (int)(cpack[e] & 0x1ffffu);
                fb[u] = F4[(size_t)s * 16 + l16];
                pb[u] = alphap[(size_t)e * 4 + h];
            }
        } else {
#pragma unroll
            for (int u = 0; u < 8; u++) {
                int jj = j + u;
                int e = min(max(start + min(jj, dg - 1), 0), E - 1);
                int s = (int)(cpack[e] & 0x1ffffu);
                fb[u] = F4[(size_t)s * 16 + l16];
                float pv = alphap[(size_t)e * 4 + h];
                pb[u] = (jj < dg) ? pv : 0.f;
            }
        }
    };
    auto consume = [&](const uint4* fb, const float* pb) {
#pragma unroll
        for (int u = 0; u < 8; u++) {
            float p = pb[u];
            a0 += p * __uint_as_float(fb[u].x << 16);
            a1 += p * __uint_as_float(fb[u].x & 0xffff0000u);
            a2 += p * __uint_as_float(fb[u].y << 16);
            a3 += p * __uint_as_float(fb[u].y & 0xffff0000u);
            a4 += p * __uint_as_float(fb[u].z << 16);
            a5 += p * __uint_as_float(fb[u].z & 0xffff0000u);
            a6 += p * __uint_as_float(fb[u].w << 16);
            a7 += p * __uint_as_float(fb[u].w & 0xffff0000u);
        }
    };

    uint4 f0[8], f1[8];
    float p0[8], p1[8];
    if (nccmax > 0) {
        loadc(0, f0, p0);
        for (int c = 1; c < nccmax; c++) {
            if (c & 1) { loadc(c, f1, p1); consume(f0, p0); }
            else       { loadc(c, f0, p0); consume(f1, p1); }
        }
        if (nccmax & 1) consume(f0, p0); else consume(f1, p1);
    }

    if (!active) return;
    a0 = fmaxf(a0, 0.f); a1 = fmaxf(a1, 0.f);
    a2 = fmaxf(a2, 0.f); a3 = fmaxf(a3, 0.f);
    a4 = fmaxf(a4, 0.f); a5 = fmaxf(a5, 0.f);
    a6 = fmaxf(a6, 0.f); a7 = fmaxf(a7, 0.f);
    if (OUT_BF16) {
        uint4 pk;
        pk.x = pack_bf2(a0, a1);
        pk.y = pack_bf2(a2, a3);
        pk.z = pack_bf2(a4, a5);
        pk.w = pack_bf2(a6, a7);
        ((uint4*)outp)[(size_t)node * 16 + l16] = pk;
    } else {
        float4* op = (float4*)outp + (size_t)node * 32 + l16 * 2;
        op[0] = make_float4(a0, a1, a2, a3);
        op[1] = make_float4(a4, a5, a6, a7);
    }
}

// ---------------- launch ----------------

extern "C" void kernel_launch(void* const* d_in, const int* in_sizes, int n_in,
                              void* d_out, int out_size, void* d_ws, size_t ws_size,
                              hipStream_t stream) {
    const float* x = (const float*)d_in[0];
    const int* ei = (const int*)d_in[1];
    int N = in_sizes[0] / 128;       // 100000
    int E = in_sizes[1] / 2;         // 1600000
    const int* src = ei;
    const int* dst = ei + E;
    const float* Wm[3] = {(const float*)d_in[2], (const float*)d_in[5], (const float*)d_in[8]};
    const float* al[3] = {(const float*)d_in[3], (const float*)d_in[6], (const float*)d_in[9]};
    const float* ar[3] = {(const float*)d_in[4], (const float*)d_in[7], (const float*)d_in[10]};

    char* p = (char*)d_ws;
    auto carve = [&](size_t bytes) {
        char* r = p;
        p += (bytes + 255) & ~(size_t)255;
        return r;
    };
    unsigned short* Xb = (unsigned short*)carve((size_t)N * 128 * 2);
    unsigned short* Hb = (unsigned short*)carve((size_t)N * 128 * 2);
    unsigned short* Fb = (unsigned short*)carve((size_t)N * 128 * 2);
    unsigned short* Wt = (unsigned short*)carve((size_t)3 * 16384 * 2);
    float* el       = (float*)carve((size_t)N * 4 * 4);
    float* er       = (float*)carve((size_t)N * 4 * 4);
    float* pw       = (float*)carve((size_t)E * 4 * 4);
    int* rowstart   = (int*)carve((size_t)(N + 1) * 4);
    unsigned* cpack = (unsigned*)carve((size_t)E * 4);
    unsigned* packed= (unsigned*)carve((size_t)E * 4);
    int* order      = (int*)carve((size_t)N * 4);
    int* bcnt       = (int*)carve((size_t)NBUCK * 4);
    int* bbase      = (int*)carve((size_t)(NBUCK + 1) * 4);
    int* bcur       = (int*)carve((size_t)NBUCK * 4);
    int* dcnt       = (int*)carve(64 * 4);
    int* dcur       = (int*)carve(64 * 4);

    int NBUSED = (N + 255) >> 8;     // 391
    int NDB = (N + DCHUNK - 1) / DCHUNK;

    // ---- CSR build (once) ----
    hipMemsetAsync(bcnt, 0, NBUCK * 4, stream);
    hipMemsetAsync(dcnt, 0, 64 * 4, stream);
    int nbB = (E + BHCHUNK - 1) / BHCHUNK;
    int n8 = N * 128 / 8;
    int nbCvt = (n8 + 255) / 256;
    int nbPrep = (3 * 16384) / 256;
    k_front<<<nbB + nbCvt + nbPrep, 256, 0, stream>>>(
        dst, bcnt, E, (const float4*)x, (uint4*)Xb, n8,
        Wm[0], Wm[1], Wm[2], Wt, nbB, nbCvt);
    k_bscan<<<1, NBUCK, 0, stream>>>(bcnt, bbase, bcur, rowstart, N, E);
    k_bin<<<(E + BCHUNK - 1) / BCHUNK, 256, 0, stream>>>(src, dst, bcur, packed, E);
    k_place2<<<NBUSED, 256, 0, stream>>>(packed, bbase, rowstart, cpack, N);
    // degree-grouped node order (balances k_aggr waves)
    k_dsort1<<<NDB, 256, 0, stream>>>(rowstart, dcnt, N);
    k_dscan<<<1, 64, 0, stream>>>(dcnt, dcur);
    k_dsort2<<<NDB, 256, 0, stream>>>(rowstart, dcur, order, N);

    // ---- 3 GAT layers ----
    int gb = (N + 127) / 128;
    int ab = (N + 15) / 16;
    k_gemm<<<gb, 256, 0, stream>>>(Xb, Wt, al[0], ar[0], Fb, el, er, N);
    k_edge<<<NBUSED, 256, 0, stream>>>(cpack, bbase, (const float4*)el, (const float4*)er,
                                       (float4*)pw);
    k_aggr<1><<<ab, 256, 0, stream>>>(rowstart, order, cpack, pw, (const uint4*)Fb, Hb, N, E);

    k_gemm<<<gb, 256, 0, stream>>>(Hb, Wt + 16384, al[1], ar[1], Fb, el, er, N);
    k_edge<<<NBUSED, 256, 0, stream>>>(cpack, bbase, (const float4*)el, (const float4*)er,
                                       (float4*)pw);
    k_aggr<1><<<ab, 256, 0, stream>>>(rowstart, order, cpack, pw, (const uint4*)Fb, Hb, N, E);

    k_gemm<<<gb, 256, 0, stream>>>(Hb, Wt + 32768, al[2], ar[2], Fb, el, er, N);
    k_edge<<<NBUSED, 256, 0, stream>>>(cpack, bbase, (const float4*)el, (const float4*)er,
                                       (float4*)pw);
    k_aggr<0><<<ab, 256, 0, stream>>>(rowstart, order, cpack, pw, (const uint4*)Fb, d_out, N, E);
}

// Round 8
// 527.941 us; speedup vs baseline: 1.3145x; 1.3145x over previous
//
#include <hip/hip_runtime.h>
#include <math.h>

#define NEG_SLOPE 0.2f
#define NBUCK 512      // dst buckets of 256 nodes
#define BHCHUNK 8192   // edges per histogram block
#define BCHUNK 4096    // edges per k_bin block
#define ESLICE 4       // blocks per bucket in k_edge

typedef __attribute__((ext_vector_type(8))) short short8;   // 8 bf16 (MFMA A/B frag)
typedef __attribute__((ext_vector_type(4))) float f32x4;    // MFMA C/D frag

__device__ __forceinline__ unsigned short bf16rne(float x) {
    unsigned u = __float_as_uint(x);
    u += 0x7fffu + ((u >> 16) & 1u);
    return (unsigned short)(u >> 16);
}
__device__ __forceinline__ unsigned pack_bf2(float x, float y) {
    unsigned ux = __float_as_uint(x), uy = __float_as_uint(y);
    ux = (ux + 0x7fffu + ((ux >> 16) & 1u)) >> 16;
    uy = (uy + 0x7fffu + ((uy >> 16) & 1u)) & 0xffff0000u;
    return ux | uy;
}

// ---------------- fused front: bucket-hist + x->bf16 + W->Wt ----------------
__global__ __launch_bounds__(256) void k_front(
    const int* __restrict__ dst, int* __restrict__ bcnt, int E,
    const float4* __restrict__ x, uint4* __restrict__ Xb, int n8,
    const float* __restrict__ w0, const float* __restrict__ w1,
    const float* __restrict__ w2, unsigned short* __restrict__ Wt,
    int nbB, int nbCvt) {
    __shared__ int cnt[NBUCK];
    int bb = blockIdx.x, t = threadIdx.x;
    if (bb < nbB) {
        for (int i = t; i < NBUCK; i += 256) cnt[i] = 0;
        __syncthreads();
        int e0 = bb * BHCHUNK;
        int n = min(BHCHUNK, E - e0);
        for (int i = t; i < n; i += 256) atomicAdd(&cnt[dst[e0 + i] >> 8], 1);
        __syncthreads();
        for (int i = t; i < NBUCK; i += 256)
            if (cnt[i]) atomicAdd(&bcnt[i], cnt[i]);
    } else if (bb < nbB + nbCvt) {
        int id = (bb - nbB) * 256 + t;
        if (id < n8) {
            float4 a = x[id * 2], b = x[id * 2 + 1];
            uint4 o;
            o.x = pack_bf2(a.x, a.y);
            o.y = pack_bf2(a.z, a.w);
            o.z = pack_bf2(b.x, b.y);
            o.w = pack_bf2(b.z, b.w);
            Xb[id] = o;
        }
    } else {
        int id = (bb - nbB - nbCvt) * 256 + t;    // 3*16384 ids
        int layer = id >> 14, rem = id & 16383;
        int k = rem >> 7, n = rem & 127;
        const float* W = (layer == 0) ? w0 : (layer == 1) ? w1 : w2;
        Wt[layer * 16384 + n * 128 + k] = bf16rne(W[k * 128 + n]);
    }
}

// ---------------- bucket scan (one block, 512 threads) ----------------
__global__ void k_bscan(const int* __restrict__ bcnt, int* __restrict__ bbase,
                        int* __restrict__ bcur, int* __restrict__ rowstart,
                        int N, int E) {
    __shared__ int sd[NBUCK];
    int t = threadIdx.x;
    int c = bcnt[t];
    sd[t] = c;
    __syncthreads();
    for (int s = 1; s < NBUCK; s <<= 1) {
        int x = (t >= s) ? sd[t - s] : 0;
        __syncthreads();
        sd[t] += x;
        __syncthreads();
    }
    int excl = sd[t] - c;
    bbase[t] = excl;
    bcur[t] = excl;
    if (t == NBUCK - 1) bbase[NBUCK] = excl + c;   // == E
    if (t == 0) rowstart[N] = E;
}

// ---------------- bin edges into buckets (contiguous packed runs) ----------------
__global__ __launch_bounds__(256) void k_bin(
    const int* __restrict__ src, const int* __restrict__ dst,
    int* __restrict__ bcur, unsigned* __restrict__ packed, int E) {
    __shared__ int cnt[NBUCK];
    __shared__ int gbase[NBUCK];
    for (int i = threadIdx.x; i < NBUCK; i += 256) cnt[i] = 0;
    __syncthreads();
    int e0 = blockIdx.x * BCHUNK;
    int n = min(BCHUNK, E - e0);
    for (int i = threadIdx.x; i < n; i += 256)
        atomicAdd(&cnt[dst[e0 + i] >> 8], 1);
    __syncthreads();
    for (int i = threadIdx.x; i < NBUCK; i += 256) {
        int c = cnt[i];
        gbase[i] = c ? atomicAdd(&bcur[i], c) : 0;
        cnt[i] = 0;
    }
    __syncthreads();
    for (int i = threadIdx.x; i < n; i += 256) {
        int d = dst[e0 + i];
        int b = d >> 8;
        int o = atomicAdd(&cnt[b], 1);
        packed[gbase[b] + o] = ((unsigned)src[e0 + i] << 8) | (unsigned)(d & 255);
    }
}

// ---------------- per-bucket: node hist + scan -> rowstart; place via LDS cursors ----
// cpack entry = (dst_local<<17) | src  (src < 2^17).
__global__ __launch_bounds__(256) void k_place2(
    const unsigned* __restrict__ packed, const int* __restrict__ bbase,
    int* __restrict__ rowstart, unsigned* __restrict__ cpack, int N) {
    __shared__ int cnt[256], sd[256], lcur[256];
    int b = blockIdx.x, t = threadIdx.x;
    int base = bbase[b], end = bbase[b + 1];
    cnt[t] = 0;
    __syncthreads();
    for (int i = base + t; i < end; i += 256)
        atomicAdd(&cnt[packed[i] & 255u], 1);
    __syncthreads();
    sd[t] = cnt[t];
    __syncthreads();
    for (int s = 1; s < 256; s <<= 1) {
        int x = (t >= s) ? sd[t - s] : 0;
        __syncthreads();
        sd[t] += x;
        __syncthreads();
    }
    int excl = sd[t] - cnt[t];
    int gid = (b << 8) + t;
    if (gid < N) rowstart[gid] = base + excl;
    lcur[t] = base + excl;
    __syncthreads();
    for (int i = base + t; i < end; i += 256) {
        unsigned p = packed[i];
        unsigned dl = p & 255u;
        int pos = atomicAdd(&lcur[dl], 1);
        cpack[pos] = (dl << 17) | (p >> 8);
    }
}

// ---------------- MFMA GEMM + el/er epilogue (unchanged) ----------------
__global__ __launch_bounds__(256) void k_gemm(
    const unsigned short* __restrict__ Ab,   // [M][128] bf16
    const unsigned short* __restrict__ Wt,   // [128 n][128 k] bf16
    const float* __restrict__ alv, const float* __restrict__ arv,
    unsigned short* __restrict__ Fb,         // [M][128] bf16
    float* __restrict__ el, float* __restrict__ er, int M) {
    __shared__ unsigned short cst[4][32][128];
    int t = threadIdx.x;
    int wv = t >> 6, l = t & 63;
    int l15 = l & 15, quad = l >> 4;
    int row0 = blockIdx.x * 128 + wv * 32;

    f32x4 acc[2][8];
#pragma unroll
    for (int mi = 0; mi < 2; mi++)
#pragma unroll
        for (int nt = 0; nt < 8; nt++)
            acc[mi][nt] = (f32x4){0.f, 0.f, 0.f, 0.f};

    int rA0 = min(row0 + l15, M - 1);
    int rA1 = min(row0 + 16 + l15, M - 1);
    const uint4* pA0 = (const uint4*)(Ab + (size_t)rA0 * 128) + quad;
    const uint4* pA1 = (const uint4*)(Ab + (size_t)rA1 * 128) + quad;
    const uint4* pW = (const uint4*)Wt;

#pragma unroll
    for (int ks = 0; ks < 4; ks++) {
        union { uint4 u; short8 s; } a0, a1, b[8];
        a0.u = pA0[ks * 4];
        a1.u = pA1[ks * 4];
#pragma unroll
        for (int nt = 0; nt < 8; nt++)
            b[nt].u = pW[(nt * 16 + l15) * 16 + quad + ks * 4];
#pragma unroll
        for (int nt = 0; nt < 8; nt++) {
            acc[0][nt] = __builtin_amdgcn_mfma_f32_16x16x32_bf16(a0.s, b[nt].s, acc[0][nt], 0, 0, 0);
            acc[1][nt] = __builtin_amdgcn_mfma_f32_16x16x32_bf16(a1.s, b[nt].s, acc[1][nt], 0, 0, 0);
        }
    }

#pragma unroll
    for (int mi = 0; mi < 2; mi++)
#pragma unroll
        for (int nt = 0; nt < 8; nt++)
#pragma unroll
            for (int r = 0; r < 4; r++)
                cst[wv][mi * 16 + quad * 4 + r][nt * 16 + l15] = bf16rne(acc[mi][nt][r]);

    int rrow = l >> 1;
    int cb = (l & 1) * 64;
    int grow = row0 + rrow;
    bool ok = grow < M;
    float pe[2] = {0.f, 0.f}, pr[2] = {0.f, 0.f};
#pragma unroll
    for (int i = 0; i < 8; i++) {
        uint4 v = *(const uint4*)&cst[wv][rrow][cb + i * 8];
        if (ok) ((uint4*)(Fb + (size_t)grow * 128 + cb))[i] = v;
        int hi = i >> 2;
        int c0 = cb + i * 8;
        unsigned uu[4] = {v.x, v.y, v.z, v.w};
#pragma unroll
        for (int q = 0; q < 4; q++) {
            float fa = __uint_as_float(uu[q] << 16);
            float fb = __uint_as_float(uu[q] & 0xffff0000u);
            pe[hi] += fa * alv[c0 + 2 * q] + fb * alv[c0 + 2 * q + 1];
            pr[hi] += fa * arv[c0 + 2 * q] + fb * arv[c0 + 2 * q + 1];
        }
    }
    float qe0 = __shfl_xor(pe[0], 1, 64), qe1 = __shfl_xor(pe[1], 1, 64);
    float qr0 = __shfl_xor(pr[0], 1, 64), qr1 = __shfl_xor(pr[1], 1, 64);
    if (((l & 1) == 0) && ok) {
        *(float4*)&el[(size_t)grow * 4] = make_float4(pe[0], pe[1], qe0, qe1);
        *(float4*)&er[(size_t)grow * 4] = make_float4(pr[0], pr[1], qr0, qr1);
    }
}

// ---------------- edge attention: p = exp(leaky(el[s]+er[d])), single pass -------
// ESLICE blocks per bucket (grid ~1564) for occupancy; er slab L1/L2-hot.
__global__ __launch_bounds__(256) void k_edge(
    const unsigned* __restrict__ cpack, const int* __restrict__ bbase,
    const float4* __restrict__ el4, const float4* __restrict__ er4,
    float4* __restrict__ pw4) {
    int b = blockIdx.x >> 2;            // bucket
    int slice = blockIdx.x & (ESLICE - 1);
    int t = slice * 256 + threadIdx.x;
    int base = bbase[b], end = bbase[b + 1];
    for (int i = base + t; i < end; i += 256 * ESLICE) {
        unsigned w = cpack[i];
        int s = (int)(w & 0x1ffffu);
        int d = (b << 8) + (int)(w >> 17);
        float4 l = el4[s], r = er4[d];
        float4 o;
        float e;
        e = l.x + r.x; e = fmaxf(e, NEG_SLOPE * e); o.x = __expf(e);
        e = l.y + r.y; e = fmaxf(e, NEG_SLOPE * e); o.y = __expf(e);
        e = l.z + r.z; e = fmaxf(e, NEG_SLOPE * e); o.z = __expf(e);
        e = l.w + r.w; e = fmaxf(e, NEG_SLOPE * e); o.w = __expf(e);
        pw4[i] = o;
    }
}

// ---------------- aggregation: 4 nodes/wave, 16 lanes x 8 features ----------
// Natural node order (coalesced writes, no sorted-tail). Lane l16 owns features
// [l16*8, l16*8+8) = one uint4 of bf16 per gathered row; p unnormalized (s_acc
// inline, redundant across the 4 lanes of a head — 1 add/edge). 4-deep ping-pong
// chunks keep VGPR ~60 (8 waves/SIMD) while holding 8 gathers in flight.
template <int OUT_BF16>
__global__ __launch_bounds__(256) void k_aggr(
    const int* __restrict__ rowstart, const unsigned* __restrict__ cpack,
    const float* __restrict__ pw, const uint4* __restrict__ F4,
    void* __restrict__ outp, int N, int E) {
    int lane = threadIdx.x & 63;
    int sub = lane >> 4;           // node slot in wave
    int l16 = lane & 15;
    int w = blockIdx.x * 16 + ((threadIdx.x >> 6) << 2) + sub;
    bool active = w < N;
    int wc = active ? w : N - 1;
    int start = rowstart[wc];
    int dg = active ? (rowstart[wc + 1] - start) : 0;
    int h = l16 >> 2;

    float s_acc = 0.f;
    float a0 = 0.f, a1 = 0.f, a2 = 0.f, a3 = 0.f;
    float a4 = 0.f, a5 = 0.f, a6 = 0.f, a7 = 0.f;

    int ncc = (dg + 3) >> 2;
    int m = max(ncc, __shfl_xor(ncc, 16, 64));
    int nccmax = max(m, __shfl_xor(m, 32, 64));
    int full = dg >> 2;
    int mf = min(full, __shfl_xor(full, 16, 64));
    int minfull = min(mf, __shfl_xor(mf, 32, 64));   // wave-uniform

    auto loadc = [&](int c, uint4* fb, float* pb) {
        int j = c << 2;
        if (c < minfull) {
#pragma unroll
            for (int u = 0; u < 4; u++) {
                int e = start + j + u;
                int s = (int)(cpack[e] & 0x1ffffu);
                fb[u] = F4[(size_t)s * 16 + l16];
                pb[u] = pw[(size_t)e * 4 + h];
            }
        } else {
#pragma unroll
            for (int u = 0; u < 4; u++) {
                int jj = j + u;
                int e = min(max(start + min(jj, dg - 1), 0), E - 1);
                int s = (int)(cpack[e] & 0x1ffffu);
                fb[u] = F4[(size_t)s * 16 + l16];
                float pv = pw[(size_t)e * 4 + h];
                pb[u] = (jj < dg) ? pv : 0.f;
            }
        }
    };
    auto consume = [&](const uint4* fb, const float* pb) {
#pragma unroll
        for (int u = 0; u < 4; u++) {
            float p = pb[u];
            s_acc += p;
            a0 += p * __uint_as_float(fb[u].x << 16);
            a1 += p * __uint_as_float(fb[u].x & 0xffff0000u);
            a2 += p * __uint_as_float(fb[u].y << 16);
            a3 += p * __uint_as_float(fb[u].y & 0xffff0000u);
            a4 += p * __uint_as_float(fb[u].z << 16);
            a5 += p * __uint_as_float(fb[u].z & 0xffff0000u);
            a6 += p * __uint_as_float(fb[u].w << 16);
            a7 += p * __uint_as_float(fb[u].w & 0xffff0000u);
        }
    };

    uint4 f0[4], f1[4];
    float p0[4], p1[4];
    if (nccmax > 0) {
        loadc(0, f0, p0);
        for (int c = 1; c < nccmax; c++) {
            if (c & 1) { loadc(c, f1, p1); consume(f0, p0); }
            else       { loadc(c, f0, p0); consume(f1, p1); }
        }
        if (nccmax & 1) consume(f0, p0); else consume(f1, p1);
    }

    if (!active) return;
    float inv = 1.f / (s_acc + 1e-9f);
    a0 = fmaxf(a0 * inv, 0.f); a1 = fmaxf(a1 * inv, 0.f);
    a2 = fmaxf(a2 * inv, 0.f); a3 = fmaxf(a3 * inv, 0.f);
    a4 = fmaxf(a4 * inv, 0.f); a5 = fmaxf(a5 * inv, 0.f);
    a6 = fmaxf(a6 * inv, 0.f); a7 = fmaxf(a7 * inv, 0.f);
    if (OUT_BF16) {
        uint4 pk;
        pk.x = pack_bf2(a0, a1);
        pk.y = pack_bf2(a2, a3);
        pk.z = pack_bf2(a4, a5);
        pk.w = pack_bf2(a6, a7);
        ((uint4*)outp)[(size_t)w * 16 + l16] = pk;
    } else {
        float4* op = (float4*)outp + (size_t)w * 32 + l16 * 2;
        op[0] = make_float4(a0, a1, a2, a3);
        op[1] = make_float4(a4, a5, a6, a7);
    }
}

// ---------------- launch ----------------

extern "C" void kernel_launch(void* const* d_in, const int* in_sizes, int n_in,
                              void* d_out, int out_size, void* d_ws, size_t ws_size,
                              hipStream_t stream) {
    const float* x = (const float*)d_in[0];
    const int* ei = (const int*)d_in[1];
    int N = in_sizes[0] / 128;       // 100000
    int E = in_sizes[1] / 2;         // 1600000
    const int* src = ei;
    const int* dst = ei + E;
    const float* Wm[3] = {(const float*)d_in[2], (const float*)d_in[5], (const float*)d_in[8]};
    const float* al[3] = {(const float*)d_in[3], (const float*)d_in[6], (const float*)d_in[9]};
    const float* ar[3] = {(const float*)d_in[4], (const float*)d_in[7], (const float*)d_in[10]};

    char* p = (char*)d_ws;
    auto carve = [&](size_t bytes) {
        char* r = p;
        p += (bytes + 255) & ~(size_t)255;
        return r;
    };
    unsigned short* Xb = (unsigned short*)carve((size_t)N * 128 * 2);
    unsigned short* Hb = (unsigned short*)carve((size_t)N * 128 * 2);
    unsigned short* Fb = (unsigned short*)carve((size_t)N * 128 * 2);
    unsigned short* Wt = (unsigned short*)carve((size_t)3 * 16384 * 2);
    float* el       = (float*)carve((size_t)N * 4 * 4);
    float* er       = (float*)carve((size_t)N * 4 * 4);
    float* pw       = (float*)carve((size_t)E * 4 * 4);
    int* rowstart   = (int*)carve((size_t)(N + 1) * 4);
    unsigned* cpack = (unsigned*)carve((size_t)E * 4);
    unsigned* packed= (unsigned*)carve((size_t)E * 4);
    int* bcnt       = (int*)carve((size_t)NBUCK * 4);
    int* bbase      = (int*)carve((size_t)(NBUCK + 1) * 4);
    int* bcur       = (int*)carve((size_t)NBUCK * 4);

    int NBUSED = (N + 255) >> 8;     // 391

    // ---- CSR build (once) ----
    hipMemsetAsync(bcnt, 0, NBUCK * 4, stream);
    int nbB = (E + BHCHUNK - 1) / BHCHUNK;
    int n8 = N * 128 / 8;
    int nbCvt = (n8 + 255) / 256;
    int nbPrep = (3 * 16384) / 256;
    k_front<<<nbB + nbCvt + nbPrep, 256, 0, stream>>>(
        dst, bcnt, E, (const float4*)x, (uint4*)Xb, n8,
        Wm[0], Wm[1], Wm[2], Wt, nbB, nbCvt);
    k_bscan<<<1, NBUCK, 0, stream>>>(bcnt, bbase, bcur, rowstart, N, E);
    k_bin<<<(E + BCHUNK - 1) / BCHUNK, 256, 0, stream>>>(src, dst, bcur, packed, E);
    k_place2<<<NBUSED, 256, 0, stream>>>(packed, bbase, rowstart, cpack, N);

    // ---- 3 GAT layers ----
    int gb = (N + 127) / 128;
    int ab = (N + 15) / 16;
    k_gemm<<<gb, 256, 0, stream>>>(Xb, Wt, al[0], ar[0], Fb, el, er, N);
    k_edge<<<NBUSED * ESLICE, 256, 0, stream>>>(cpack, bbase, (const float4*)el,
                                                (const float4*)er, (float4*)pw);
    k_aggr<1><<<ab, 256, 0, stream>>>(rowstart, cpack, pw, (const uint4*)Fb, Hb, N, E);

    k_gemm<<<gb, 256, 0, stream>>>(Hb, Wt + 16384, al[1], ar[1], Fb, el, er, N);
    k_edge<<<NBUSED * ESLICE, 256, 0, stream>>>(cpack, bbase, (const float4*)el,
                                                (const float4*)er, (float4*)pw);
    k_aggr<1><<<ab, 256, 0, stream>>>(rowstart, cpack, pw, (const uint4*)Fb, Hb, N, E);

    k_gemm<<<gb, 256, 0, stream>>>(Hb, Wt + 32768, al[2], ar[2], Fb, el, er, N);
    k_edge<<<NBUSED * ESLICE, 256, 0, stream>>>(cpack, bbase, (const float4*)el,
                                                (const float4*)er, (float4*)pw);
    k_aggr<0><<<ab, 256, 0, stream>>>(rowstart, cpack, pw, (const uint4*)Fb, d_out, N, E);
}